// Round 15
// baseline (237.633 us; speedup 1.0000x reference)
//
#include <hip/hip_runtime.h>
#include <hip/hip_bf16.h>

typedef __attribute__((ext_vector_type(8))) _Float16 half8;
typedef __attribute__((ext_vector_type(4))) float f32x4;
typedef __attribute__((ext_vector_type(4))) float float4v;

#define NPB 256        // nodes per bucket (dst >> 8)
#define PBLK 256       // partition blocks
#define BCAP 6144      // padded bucket capacity (mean 4092, std 64 -> 32 sigma margin)

// ---------------- init: gcur[b] = b * BCAP ----------------
__global__ __launch_bounds__(256) void init_gcur(int* __restrict__ gcur, int NB) {
    int i = blockIdx.x * 256 + threadIdx.x;
    if (i < NB) gcur[i] = i * BCAP;
}

// ---------------- single-pass partition: LDS histogram + atomic chunk reservation ----------------
// edge record = uint2{ src | dlocal<<20, bits(ew) }
__global__ __launch_bounds__(256) void part1(const int* __restrict__ src,
                                             const int* __restrict__ dst,
                                             const float* __restrict__ ew,
                                             int* __restrict__ gcur,
                                             uint2* __restrict__ edg,
                                             int E, int NB, int chunk) {
    __shared__ int h[512];
    __shared__ int cur[512];
    int t = threadIdx.x, p = blockIdx.x;
    for (int i = t; i < NB; i += 256) h[i] = 0;
    __syncthreads();
    int beg = p * chunk, end = min(beg + chunk, E);
    for (int e = beg + t; e < end; e += 256) atomicAdd(&h[dst[e] >> 8], 1);
    __syncthreads();
    for (int b = t; b < NB; b += 256) {
        int c = h[b];
        cur[b] = (c > 0) ? atomicAdd(&gcur[b], c) : 0;
    }
    __syncthreads();
    for (int e = beg + t; e < end; e += 256) {
        int d = dst[e];
        int b = d >> 8;
        int pos = atomicAdd(&cur[b], 1);
        uint2 rec;
        rec.x = (unsigned)src[e] | ((unsigned)(d & 255) << 20);
        rec.y = __float_as_uint(ew[e]);
        edg[pos] = rec;
    }
}

// ---------------- p3: per-bucket CSR (padded layout) + degree + dinv ----------------
// bucket b edges: [b*BCAP, gcur[b])
__global__ __launch_bounds__(256) void p3_bucket(const uint2* __restrict__ edg,
                                                 const int* __restrict__ gcur,
                                                 uint2* __restrict__ edgf,
                                                 int* __restrict__ rowbeg,
                                                 int* __restrict__ rowend,
                                                 float* __restrict__ dinv,
                                                 int N, int NB) {
    __shared__ int cnt[256];
    __shared__ float wd[256];
    __shared__ int ls[256];
    __shared__ int cur[256];
    int t = threadIdx.x, b = blockIdx.x;
    int beg = b * BCAP;
    int end = gcur[b];
    cnt[t] = 0;
    wd[t] = 0.0f;
    __syncthreads();
    for (int e = beg + t; e < end; e += 256) {
        uint2 v = edg[e];
        int dl = v.x >> 20;
        atomicAdd(&cnt[dl], 1);
        atomicAdd(&wd[dl], __uint_as_float(v.y));
    }
    __syncthreads();
    ls[t] = cnt[t];
    __syncthreads();
    for (int off = 1; off < 256; off <<= 1) {
        int add = (t >= off) ? ls[t - off] : 0;
        __syncthreads();
        ls[t] += add;
        __syncthreads();
    }
    int excl = (t == 0) ? 0 : ls[t - 1];
    int node = b * NPB + t;
    if (node < N) {
        rowbeg[node] = beg + excl;
        rowend[node] = beg + excl + cnt[t];
        dinv[node] = rsqrtf(1.0f + wd[t]);   // +1 = self-loop weight
    }
    cur[t] = beg + excl;
    __syncthreads();
    for (int e = beg + t; e < end; e += 256) {
        uint2 v = edg[e];
        int dl = v.x >> 20;
        int pos = atomicAdd(&cur[dl], 1);
        uint2 rec;
        rec.x = v.x & 0xFFFFF;
        rec.y = v.y;
        edgf[pos] = rec;
    }
}

// ---------------- split_scale: xs = fp16(dinv .* x) ----------------
__global__ __launch_bounds__(256) void split_scale(const float* __restrict__ x,
                                                   const float* __restrict__ dinv,
                                                   _Float16* __restrict__ xs,
                                                   int nquad) {   // nquad = N*32 float4s
    int i = blockIdx.x * 256 + threadIdx.x;
    if (i >= nquad) return;
    float4v v = ((const float4v*)x)[i];
    float s = dinv[i >> 5];   // 32 float4s per 128-col row
    union { uint2 u; _Float16 h[4]; } o;
    o.h[0] = (_Float16)(s * v[0]);
    o.h[1] = (_Float16)(s * v[1]);
    o.h[2] = (_Float16)(s * v[2]);
    o.h[3] = (_Float16)(s * v[3]);
    ((uint2*)xs)[i] = o.u;
}

// ---------------- aggregation: 2 independent node streams per wave ----------------
// t = fp16(dinv.*(sum ew*F[src] + F[self])); edges as interleaved uint2 records.
__global__ __launch_bounds__(256) void agg_kernel(const _Float16* __restrict__ F,
                                                  const int* __restrict__ rowbeg,
                                                  const int* __restrict__ rowend,
                                                  const uint2* __restrict__ edg,
                                                  const float* __restrict__ dinv,
                                                  unsigned* __restrict__ ttU, int n) {
    const unsigned* Fu = (const unsigned*)F;   // one uint = 2 fp16 cols
    int wid  = (blockIdx.x * 256 + threadIdx.x) >> 6;
    int lane = threadIdx.x & 63;
    int n0 = __builtin_amdgcn_readfirstlane(wid) * 2;
    if (n0 >= n) return;
    const bool has1 = (n0 + 1) < n;

    int e0   = rowbeg[n0];
    int end0 = rowend[n0];
    int e1   = has1 ? rowbeg[n0 + 1] : 0;
    int end1 = has1 ? rowend[n0 + 1] : 0;
    float di0 = dinv[n0];
    float di1 = has1 ? dinv[n0 + 1] : 0.0f;

    union { unsigned u; _Float16 h[2]; } cv;
    cv.u = Fu[(size_t)n0 * 64 + lane];
    float a0x = (float)cv.h[0], a0y = (float)cv.h[1];
    float a1x = 0.0f, a1y = 0.0f;
    if (has1) {
        cv.u = Fu[(size_t)(n0 + 1) * 64 + lane];
        a1x = (float)cv.h[0];
        a1y = (float)cv.h[1];
    }

    while (e0 + 8 <= end0 && e1 + 8 <= end1) {
        uint2 rA[8], rB[8];
        unsigned vA[8], vB[8];
#pragma unroll
        for (int j = 0; j < 8; ++j) rA[j] = edg[e0 + j];
#pragma unroll
        for (int j = 0; j < 8; ++j) rB[j] = edg[e1 + j];
#pragma unroll
        for (int j = 0; j < 8; ++j) vA[j] = Fu[(size_t)rA[j].x * 64 + lane];
#pragma unroll
        for (int j = 0; j < 8; ++j) vB[j] = Fu[(size_t)rB[j].x * 64 + lane];
#pragma unroll
        for (int j = 0; j < 8; ++j) {
            float w = __uint_as_float(rA[j].y);
            cv.u = vA[j];
            a0x += w * (float)cv.h[0];
            a0y += w * (float)cv.h[1];
        }
#pragma unroll
        for (int j = 0; j < 8; ++j) {
            float w = __uint_as_float(rB[j].y);
            cv.u = vB[j];
            a1x += w * (float)cv.h[0];
            a1y += w * (float)cv.h[1];
        }
        e0 += 8;
        e1 += 8;
    }
    for (; e0 + 8 <= end0; e0 += 8) {
        uint2 r_[8];
        unsigned v_[8];
#pragma unroll
        for (int j = 0; j < 8; ++j) r_[j] = edg[e0 + j];
#pragma unroll
        for (int j = 0; j < 8; ++j) v_[j] = Fu[(size_t)r_[j].x * 64 + lane];
#pragma unroll
        for (int j = 0; j < 8; ++j) {
            float w = __uint_as_float(r_[j].y);
            cv.u = v_[j];
            a0x += w * (float)cv.h[0];
            a0y += w * (float)cv.h[1];
        }
    }
    for (; e1 + 8 <= end1; e1 += 8) {
        uint2 r_[8];
        unsigned v_[8];
#pragma unroll
        for (int j = 0; j < 8; ++j) r_[j] = edg[e1 + j];
#pragma unroll
        for (int j = 0; j < 8; ++j) v_[j] = Fu[(size_t)r_[j].x * 64 + lane];
#pragma unroll
        for (int j = 0; j < 8; ++j) {
            float w = __uint_as_float(r_[j].y);
            cv.u = v_[j];
            a1x += w * (float)cv.h[0];
            a1y += w * (float)cv.h[1];
        }
    }
    for (; e0 < end0; ++e0) {
        uint2 r = edg[e0];
        float w = __uint_as_float(r.y);
        cv.u = Fu[(size_t)r.x * 64 + lane];
        a0x += w * (float)cv.h[0];
        a0y += w * (float)cv.h[1];
    }
    for (; e1 < end1; ++e1) {
        uint2 r = edg[e1];
        float w = __uint_as_float(r.y);
        cv.u = Fu[(size_t)r.x * 64 + lane];
        a1x += w * (float)cv.h[0];
        a1y += w * (float)cv.h[1];
    }

    union { unsigned u; _Float16 h[2]; } o;
    o.h[0] = (_Float16)(di0 * a0x);
    o.h[1] = (_Float16)(di0 * a0y);
    ttU[(size_t)n0 * 64 + lane] = o.u;
    if (has1) {
        o.h[0] = (_Float16)(di1 * a1x);
        o.h[1] = (_Float16)(di1 * a1y);
        ttU[(size_t)(n0 + 1) * 64 + lane] = o.u;
    }
}

// ---------------- MFMA GEMM (fp16, LDS-staged W, swapped operands) ----------------
// out = relu(A @ W + b). Operand swap mfma(W_frag, t_frag): D is transposed so each
// lane holds 4 CONSECUTIVE output columns of one row -> packed uint2/float4 stores.
// mode 0: outb = fp16(dinv .* relu(..));  mode 1: outf = relu(..)
__global__ __launch_bounds__(256, 3) void gemm_mfma(const _Float16* __restrict__ A,
                                                    const float* __restrict__ W,
                                                    const float* __restrict__ bias,
                                                    const float* __restrict__ dinv,
                                                    _Float16* __restrict__ outb,
                                                    float* __restrict__ outf,
                                                    int nrows, int mode) {
    __shared__ _Float16 sW[128 * 128];   // [c][k], swizzled

    const int t = threadIdx.x;

    // ---- stage W transposed [c][k]: coalesced reads, b128 LDS writes ----
    {
        const int c = t & 127;
        const int kg0 = t >> 7;   // 0..1
#pragma unroll
        for (int it = 0; it < 8; ++it) {
            int kg = kg0 + it * 2;   // 0..15
            half8 h8;
#pragma unroll
            for (int j = 0; j < 8; ++j)
                h8[j] = (_Float16)W[(size_t)(kg * 8 + j) * 128 + c];
            int idx = (c * 128 + kg * 8) ^ ((c & 7) << 3);
            *(half8*)&sW[idx] = h8;
        }
    }
    __syncthreads();   // the only barrier

    const int lane = t & 63;
    const int fr = lane & 15;      // row index within 16-row block / W-col sub-index
    const int kq = lane >> 4;      // 0..3

    const int wid = blockIdx.x * 4 + (t >> 6);      // one 32-row panel per wave
    const int npan = (nrows + 31) >> 5;
    if (wid >= npan) return;
    const int r0 = wid * 32;

    // bias: 4 consecutive cols per lane per fc
    float4v bv4[8];
#pragma unroll
    for (int fc = 0; fc < 8; ++fc)
        bv4[fc] = *(const float4v*)(bias + fc * 16 + kq * 4);

    const half8 z8 = {0, 0, 0, 0, 0, 0, 0, 0};

#define LOADA(KS, AH)                                                         \
    {                                                                         \
        _Pragma("unroll")                                                     \
        for (int rf_ = 0; rf_ < 2; ++rf_) {                                   \
            int row_ = r0 + rf_ * 16 + fr;                                    \
            if (row_ < nrows) {                                               \
                AH[rf_] = *(const half8*)(A + (size_t)row_ * 128 + (KS) * 32 + kq * 8); \
            } else {                                                          \
                AH[rf_] = z8;                                                 \
            }                                                                 \
        }                                                                     \
    }

// swapped operands: mfma(W_frag, t_frag) -> D[col = t-row(fr), row = W-col(kq*4+reg)]
#define KSTEP(KS, AH)                                                         \
    {                                                                         \
        _Pragma("unroll")                                                     \
        for (int fc_ = 0; fc_ < 8; ++fc_) {                                   \
            int c_ = fc_ * 16 + fr;                                           \
            int bidx_ = (c_ * 128 + (KS) * 32 + kq * 8) ^ ((c_ & 7) << 3);    \
            half8 w_ = *(half8*)&sW[bidx_];                                   \
            _Pragma("unroll")                                                 \
            for (int rf_ = 0; rf_ < 2; ++rf_) {                               \
                acc[rf_][fc_] = __builtin_amdgcn_mfma_f32_16x16x32_f16(       \
                    w_, AH[rf_], acc[rf_][fc_], 0, 0, 0);                     \
            }                                                                 \
        }                                                                     \
    }

    f32x4 acc[2][8];
#pragma unroll
    for (int rf = 0; rf < 2; ++rf)
#pragma unroll
        for (int fc = 0; fc < 8; ++fc) acc[rf][fc] = (f32x4){0.f, 0.f, 0.f, 0.f};

    half8 aA[2], aB[2];
    LOADA(0, aA);
    LOADA(1, aB);
    KSTEP(0, aA);
    LOADA(2, aA);
    KSTEP(1, aB);
    LOADA(3, aB);
    KSTEP(2, aA);
    KSTEP(3, aB);

#undef LOADA
#undef KSTEP

    // ---- epilogue: lane owns row (r0+rf*16+fr), cols fc*16+kq*4 .. +3 ----
    if (mode == 0) {
#pragma unroll
        for (int rf = 0; rf < 2; ++rf) {
            int grow = r0 + rf * 16 + fr;
            if (grow < nrows) {
                float s = dinv[grow];
#pragma unroll
                for (int fc = 0; fc < 8; ++fc) {
                    union { uint2 u; _Float16 h[4]; } o;
#pragma unroll
                    for (int rg = 0; rg < 4; ++rg)
                        o.h[rg] = (_Float16)(s * fmaxf(acc[rf][fc][rg] + bv4[fc][rg], 0.0f));
                    *(uint2*)(outb + (size_t)grow * 128 + fc * 16 + kq * 4) = o.u;
                }
            }
        }
    } else {
#pragma unroll
        for (int rf = 0; rf < 2; ++rf) {
            int grow = r0 + rf * 16 + fr;
            if (grow < nrows) {
#pragma unroll
                for (int fc = 0; fc < 8; ++fc) {
                    float4v o;
#pragma unroll
                    for (int rg = 0; rg < 4; ++rg)
                        o[rg] = fmaxf(acc[rf][fc][rg] + bv4[fc][rg], 0.0f);
                    *(float4v*)(outf + (size_t)grow * 128 + fc * 16 + kq * 4) = o;
                }
            }
        }
    }
}

// ---------------- launcher ----------------

extern "C" void kernel_launch(void* const* d_in, const int* in_sizes, int n_in,
                              void* d_out, int out_size, void* d_ws, size_t ws_size,
                              hipStream_t stream) {
    const float* x  = (const float*)d_in[0];
    const int*   ei = (const int*)d_in[1];
    const float* ew = (const float*)d_in[2];
    const float* W1 = (const float*)d_in[3];
    const float* b1 = (const float*)d_in[4];
    const float* W2 = (const float*)d_in[5];
    const float* b2 = (const float*)d_in[6];
    float* out = (float*)d_out;

    const int N = in_sizes[0] / 128;
    const int E = in_sizes[2];
    const int* src = ei;
    const int* dst = ei + E;

    const int NB = (N + NPB - 1) / NPB;        // buckets (391 for N=100k)
    const int chunk = (E + PBLK - 1) / PBLK;

    // workspace layout
    _Float16* gat  = (_Float16*)d_ws;                     // N*128 fp16 (gather features)
    _Float16* tt   = gat + (size_t)N * 128;               // N*128 fp16 (agg result t)
    uint2*   edgf  = (uint2*)(tt + (size_t)N * 128);      // NB*BCAP padded CSR edge records
    int*   rowbeg  = (int*)(edgf + (size_t)NB * BCAP);    // N
    int*   rowend  = rowbeg + N;               // N
    float* dinv    = (float*)(rowend + N);     // N
    int*   gcur    = (int*)(dinv + N);         // NB
    uint2* edg     = (uint2*)gat;              // alias (NB*BCAP uint2 = 19.2 MB < 25.6 MB; dead before gat written)

    const int npan = (N + 31) / 32;
    const int gblocks = (npan + 3) / 4;
    const int ablocks = (N + 7) / 8;           // 4 waves/block x 2 nodes/wave

    hipLaunchKernelGGL(init_gcur, dim3((NB + 255) / 256), dim3(256), 0, stream, gcur, NB);
    hipLaunchKernelGGL(part1, dim3(PBLK), dim3(256), 0, stream, src, dst, ew, gcur, edg, E, NB, chunk);
    hipLaunchKernelGGL(p3_bucket, dim3(NB), dim3(256), 0, stream, edg, gcur, edgf, rowbeg, rowend, dinv, N, NB);

    // gat = fp16(dinv .* x)   (overwrites edg alias — edg dead after p3)
    hipLaunchKernelGGL(split_scale, dim3((N * 32 + 255) / 256), dim3(256), 0, stream,
                       x, dinv, gat, N * 32);

    // layer 1: tt = fp16(dinv.*agg(gat)) ; gat = fp16(dinv.*relu(tt@W1+b1))
    hipLaunchKernelGGL(agg_kernel, dim3(ablocks), dim3(256), 0, stream,
                       gat, rowbeg, rowend, edgf, dinv, (unsigned*)tt, N);
    hipLaunchKernelGGL(gemm_mfma, dim3(gblocks), dim3(256), 0, stream,
                       tt, W1, b1, dinv, gat, (float*)nullptr, N, 0);

    // layer 2: tt = fp16(dinv.*agg(gat)) ; out = relu(tt@W2+b2)
    hipLaunchKernelGGL(agg_kernel, dim3(ablocks), dim3(256), 0, stream,
                       gat, rowbeg, rowend, edgf, dinv, (unsigned*)tt, N);
    hipLaunchKernelGGL(gemm_mfma, dim3(gblocks), dim3(256), 0, stream,
                       tt, W2, b2, dinv, (_Float16*)nullptr, out, N, 1);
}

// Round 17
// 237.037 us; speedup vs baseline: 1.0025x; 1.0025x over previous
//
#include <hip/hip_runtime.h>
#include <hip/hip_bf16.h>

typedef __attribute__((ext_vector_type(8))) _Float16 half8;
typedef __attribute__((ext_vector_type(4))) float f32x4;
typedef __attribute__((ext_vector_type(4))) float float4v;

#define NPB 256        // nodes per bucket (dst >> 8)
#define PBLK 256       // partition blocks
#define BCAP 6144      // padded bucket capacity (mean 4092, std 64 -> 32 sigma margin)

// ---------------- single-pass partition: LDS histogram + atomic chunk reservation ----------------
// gcur starts at 0 (memset); bucket b region = [b*BCAP, b*BCAP + gcur[b])
// edge record = uint2{ src | dlocal<<20, bits(ew) }
__global__ __launch_bounds__(256) void part1(const int* __restrict__ src,
                                             const int* __restrict__ dst,
                                             const float* __restrict__ ew,
                                             int* __restrict__ gcur,
                                             uint2* __restrict__ edg,
                                             int E, int NB, int chunk) {
    __shared__ int h[512];
    __shared__ int cur[512];
    int t = threadIdx.x, p = blockIdx.x;
    for (int i = t; i < NB; i += 256) h[i] = 0;
    __syncthreads();
    int beg = p * chunk, end = min(beg + chunk, E);
    for (int e = beg + t; e < end; e += 256) atomicAdd(&h[dst[e] >> 8], 1);
    __syncthreads();
    for (int b = t; b < NB; b += 256) {
        int c = h[b];
        cur[b] = b * BCAP + ((c > 0) ? atomicAdd(&gcur[b], c) : 0);
    }
    __syncthreads();
    for (int e = beg + t; e < end; e += 256) {
        int d = dst[e];
        int b = d >> 8;
        int pos = atomicAdd(&cur[b], 1);
        uint2 rec;
        rec.x = (unsigned)src[e] | ((unsigned)(d & 255) << 20);
        rec.y = __float_as_uint(ew[e]);
        edg[pos] = rec;
    }
}

// ---------------- p3: per-bucket CSR (padded layout) + degree + dinv ----------------
__global__ __launch_bounds__(256) void p3_bucket(const uint2* __restrict__ edg,
                                                 const int* __restrict__ gcur,
                                                 uint2* __restrict__ edgf,
                                                 int* __restrict__ rowbeg,
                                                 int* __restrict__ rowend,
                                                 float* __restrict__ dinv,
                                                 int N, int NB) {
    __shared__ int cnt[256];
    __shared__ float wd[256];
    __shared__ int ls[256];
    __shared__ int cur[256];
    int t = threadIdx.x, b = blockIdx.x;
    int beg = b * BCAP;
    int end = beg + gcur[b];
    cnt[t] = 0;
    wd[t] = 0.0f;
    __syncthreads();
    for (int e = beg + t; e < end; e += 256) {
        uint2 v = edg[e];
        int dl = v.x >> 20;
        atomicAdd(&cnt[dl], 1);
        atomicAdd(&wd[dl], __uint_as_float(v.y));
    }
    __syncthreads();
    ls[t] = cnt[t];
    __syncthreads();
    for (int off = 1; off < 256; off <<= 1) {
        int add = (t >= off) ? ls[t - off] : 0;
        __syncthreads();
        ls[t] += add;
        __syncthreads();
    }
    int excl = (t == 0) ? 0 : ls[t - 1];
    int node = b * NPB + t;
    if (node < N) {
        rowbeg[node] = beg + excl;
        rowend[node] = beg + excl + cnt[t];
        dinv[node] = rsqrtf(1.0f + wd[t]);   // +1 = self-loop weight
    }
    cur[t] = beg + excl;
    __syncthreads();
    for (int e = beg + t; e < end; e += 256) {
        uint2 v = edg[e];
        int dl = v.x >> 20;
        int pos = atomicAdd(&cur[dl], 1);
        uint2 rec;
        rec.x = v.x & 0xFFFFF;
        rec.y = v.y;
        edgf[pos] = rec;
    }
}

// ---------------- wconv + split_scale (fused, independent streaming jobs) ----------------
// blocks [0,128): build pre-swizzled fp16 W images (exact LDS byte image).
//   WTswz[q] = fp16( W[k*128 + c] ), c = q>>7, k = (q&127) ^ ((c&7)<<3)
// blocks [128,...): xs = fp16(dinv .* x)
__global__ __launch_bounds__(256) void wconv_split(const float* __restrict__ W1,
                                                   const float* __restrict__ W2,
                                                   _Float16* __restrict__ WT1s,
                                                   _Float16* __restrict__ WT2s,
                                                   const float* __restrict__ x,
                                                   const float* __restrict__ dinv,
                                                   _Float16* __restrict__ xs,
                                                   int nquad) {   // nquad = N*32 float4s
    int b = blockIdx.x;
    if (b < 128) {
        int p = b * 256 + threadIdx.x;     // [0, 32768)
        int w = p >> 14;                   // 0: W1, 1: W2
        int q = p & 16383;
        int c = q >> 7;
        int k = (q & 127) ^ ((c & 7) << 3);
        const float* W = w ? W2 : W1;
        _Float16* dstp = w ? WT2s : WT1s;
        dstp[q] = (_Float16)W[(size_t)k * 128 + c];
        return;
    }
    int i = (b - 128) * 256 + threadIdx.x;
    if (i >= nquad) return;
    float4v v = ((const float4v*)x)[i];
    float s = dinv[i >> 5];   // 32 float4s per 128-col row
    union { uint2 u; _Float16 h[4]; } o;
    o.h[0] = (_Float16)(s * v[0]);
    o.h[1] = (_Float16)(s * v[1]);
    o.h[2] = (_Float16)(s * v[2]);
    o.h[3] = (_Float16)(s * v[3]);
    ((uint2*)xs)[i] = o.u;
}

// ---------------- aggregation: 2 independent node streams per wave ----------------
// t = fp16(dinv.*(sum ew*F[src] + F[self])); edges as interleaved uint2 records.
__global__ __launch_bounds__(256) void agg_kernel(const _Float16* __restrict__ F,
                                                  const int* __restrict__ rowbeg,
                                                  const int* __restrict__ rowend,
                                                  const uint2* __restrict__ edg,
                                                  const float* __restrict__ dinv,
                                                  unsigned* __restrict__ ttU, int n) {
    const unsigned* Fu = (const unsigned*)F;   // one uint = 2 fp16 cols
    int wid  = (blockIdx.x * 256 + threadIdx.x) >> 6;
    int lane = threadIdx.x & 63;
    int n0 = __builtin_amdgcn_readfirstlane(wid) * 2;
    if (n0 >= n) return;
    const bool has1 = (n0 + 1) < n;

    int e0   = rowbeg[n0];
    int end0 = rowend[n0];
    int e1   = has1 ? rowbeg[n0 + 1] : 0;
    int end1 = has1 ? rowend[n0 + 1] : 0;
    float di0 = dinv[n0];
    float di1 = has1 ? dinv[n0 + 1] : 0.0f;

    union { unsigned u; _Float16 h[2]; } cv;
    cv.u = Fu[(size_t)n0 * 64 + lane];
    float a0x = (float)cv.h[0], a0y = (float)cv.h[1];
    float a1x = 0.0f, a1y = 0.0f;
    if (has1) {
        cv.u = Fu[(size_t)(n0 + 1) * 64 + lane];
        a1x = (float)cv.h[0];
        a1y = (float)cv.h[1];
    }

    while (e0 + 8 <= end0 && e1 + 8 <= end1) {
        uint2 rA[8], rB[8];
        unsigned vA[8], vB[8];
#pragma unroll
        for (int j = 0; j < 8; ++j) rA[j] = edg[e0 + j];
#pragma unroll
        for (int j = 0; j < 8; ++j) rB[j] = edg[e1 + j];
#pragma unroll
        for (int j = 0; j < 8; ++j) vA[j] = Fu[(size_t)rA[j].x * 64 + lane];
#pragma unroll
        for (int j = 0; j < 8; ++j) vB[j] = Fu[(size_t)rB[j].x * 64 + lane];
#pragma unroll
        for (int j = 0; j < 8; ++j) {
            float w = __uint_as_float(rA[j].y);
            cv.u = vA[j];
            a0x += w * (float)cv.h[0];
            a0y += w * (float)cv.h[1];
        }
#pragma unroll
        for (int j = 0; j < 8; ++j) {
            float w = __uint_as_float(rB[j].y);
            cv.u = vB[j];
            a1x += w * (float)cv.h[0];
            a1y += w * (float)cv.h[1];
        }
        e0 += 8;
        e1 += 8;
    }
    for (; e0 + 8 <= end0; e0 += 8) {
        uint2 r_[8];
        unsigned v_[8];
#pragma unroll
        for (int j = 0; j < 8; ++j) r_[j] = edg[e0 + j];
#pragma unroll
        for (int j = 0; j < 8; ++j) v_[j] = Fu[(size_t)r_[j].x * 64 + lane];
#pragma unroll
        for (int j = 0; j < 8; ++j) {
            float w = __uint_as_float(r_[j].y);
            cv.u = v_[j];
            a0x += w * (float)cv.h[0];
            a0y += w * (float)cv.h[1];
        }
    }
    for (; e1 + 8 <= end1; e1 += 8) {
        uint2 r_[8];
        unsigned v_[8];
#pragma unroll
        for (int j = 0; j < 8; ++j) r_[j] = edg[e1 + j];
#pragma unroll
        for (int j = 0; j < 8; ++j) v_[j] = Fu[(size_t)r_[j].x * 64 + lane];
#pragma unroll
        for (int j = 0; j < 8; ++j) {
            float w = __uint_as_float(r_[j].y);
            cv.u = v_[j];
            a1x += w * (float)cv.h[0];
            a1y += w * (float)cv.h[1];
        }
    }
    for (; e0 < end0; ++e0) {
        uint2 r = edg[e0];
        float w = __uint_as_float(r.y);
        cv.u = Fu[(size_t)r.x * 64 + lane];
        a0x += w * (float)cv.h[0];
        a0y += w * (float)cv.h[1];
    }
    for (; e1 < end1; ++e1) {
        uint2 r = edg[e1];
        float w = __uint_as_float(r.y);
        cv.u = Fu[(size_t)r.x * 64 + lane];
        a1x += w * (float)cv.h[0];
        a1y += w * (float)cv.h[1];
    }

    union { unsigned u; _Float16 h[2]; } o;
    o.h[0] = (_Float16)(di0 * a0x);
    o.h[1] = (_Float16)(di0 * a0y);
    ttU[(size_t)n0 * 64 + lane] = o.u;
    if (has1) {
        o.h[0] = (_Float16)(di1 * a1x);
        o.h[1] = (_Float16)(di1 * a1y);
        ttU[(size_t)(n0 + 1) * 64 + lane] = o.u;
    }
}

// ---------------- MFMA GEMM (fp16, pre-swizzled W image, swapped operands) ----------------
// Staging: 8 coalesced uint4 loads + 8 linear ds_write_b128 per thread (WTswz is the
// exact 32 KB LDS byte image). out = relu(A @ W + b), operand-swapped for packed stores.
// mode 0: outb = fp16(dinv .* relu(..));  mode 1: outf = relu(..)
__global__ __launch_bounds__(256, 3) void gemm_mfma(const _Float16* __restrict__ A,
                                                    const _Float16* __restrict__ WTswz,
                                                    const float* __restrict__ bias,
                                                    const float* __restrict__ dinv,
                                                    _Float16* __restrict__ outb,
                                                    float* __restrict__ outf,
                                                    int nrows, int mode) {
    __shared__ _Float16 sW[128 * 128];   // [c][k], swizzled (linear copy of WTswz)

    const int t = threadIdx.x;

    // ---- stage: linear 16B-chunk copy, fully coalesced (2048 uint4s total) ----
#pragma unroll
    for (int j = 0; j < 8; ++j) {
        int q = t + j * 256;
        ((uint4*)sW)[q] = ((const uint4*)WTswz)[q];
    }
    __syncthreads();   // the only barrier

    const int lane = t & 63;
    const int fr = lane & 15;      // row index within 16-row block / W-col sub-index
    const int kq = lane >> 4;      // 0..3

    const int wid = blockIdx.x * 4 + (t >> 6);      // one 32-row panel per wave
    const int npan = (nrows + 31) >> 5;
    if (wid >= npan) return;
    const int r0 = wid * 32;

    const half8 z8 = {0, 0, 0, 0, 0, 0, 0, 0};

#define LOADA(KS, AH)                                                         \
    {                                                                         \
        _Pragma("unroll")                                                     \
        for (int rf_ = 0; rf_ < 2; ++rf_) {                                   \
            int row_ = r0 + rf_ * 16 + fr;                                    \
            if (row_ < nrows) {                                               \
                AH[rf_] = *(const half8*)(A + (size_t)row_ * 128 + (KS) * 32 + kq * 8); \
            } else {                                                          \
                AH[rf_] = z8;                                                 \
            }                                                                 \
        }                                                                     \
    }

// swapped operands: mfma(W_frag, t_frag) -> D[col = t-row(fr), row = W-col(kq*4+reg)]
#define KSTEP(KS, AH)                                                         \
    {                                                                         \
        _Pragma("unroll")                                                     \
        for (int fc_ = 0; fc_ < 8; ++fc_) {                                   \
            int c_ = fc_ * 16 + fr;                                           \
            int bidx_ = (c_ * 128 + (KS) * 32 + kq * 8) ^ ((c_ & 7) << 3);    \
            half8 w_ = *(half8*)&sW[bidx_];                                   \
            _Pragma("unroll")                                                 \
            for (int rf_ = 0; rf_ < 2; ++rf_) {                               \
                acc[rf_][fc_] = __builtin_amdgcn_mfma_f32_16x16x32_f16(       \
                    w_, AH[rf_], acc[rf_][fc_], 0, 0, 0);                     \
            }                                                                 \
        }                                                                     \
    }

    f32x4 acc[2][8];
#pragma unroll
    for (int rf = 0; rf < 2; ++rf)
#pragma unroll
        for (int fc = 0; fc < 8; ++fc) acc[rf][fc] = (f32x4){0.f, 0.f, 0.f, 0.f};

    half8 aA[2], aB[2];
    LOADA(0, aA);
    LOADA(1, aB);
    KSTEP(0, aA);
    LOADA(2, aA);
    KSTEP(1, aB);
    LOADA(3, aB);
    KSTEP(2, aA);
    KSTEP(3, aB);

#undef LOADA
#undef KSTEP

    // bias: 4 consecutive cols per lane per fc
    float4v bv4[8];
#pragma unroll
    for (int fc = 0; fc < 8; ++fc)
        bv4[fc] = *(const float4v*)(bias + fc * 16 + kq * 4);

    // ---- epilogue: lane owns row (r0+rf*16+fr), cols fc*16+kq*4 .. +3 ----
    if (mode == 0) {
#pragma unroll
        for (int rf = 0; rf < 2; ++rf) {
            int grow = r0 + rf * 16 + fr;
            if (grow < nrows) {
                float s = dinv[grow];
#pragma unroll
                for (int fc = 0; fc < 8; ++fc) {
                    union { uint2 u; _Float16 h[4]; } o;
#pragma unroll
                    for (int rg = 0; rg < 4; ++rg)
                        o.h[rg] = (_Float16)(s * fmaxf(acc[rf][fc][rg] + bv4[fc][rg], 0.0f));
                    *(uint2*)(outb + (size_t)grow * 128 + fc * 16 + kq * 4) = o.u;
                }
            }
        }
    } else {
#pragma unroll
        for (int rf = 0; rf < 2; ++rf) {
            int grow = r0 + rf * 16 + fr;
            if (grow < nrows) {
#pragma unroll
                for (int fc = 0; fc < 8; ++fc) {
                    float4v o;
#pragma unroll
                    for (int rg = 0; rg < 4; ++rg)
                        o[rg] = fmaxf(acc[rf][fc][rg] + bv4[fc][rg], 0.0f);
                    *(float4v*)(outf + (size_t)grow * 128 + fc * 16 + kq * 4) = o;
                }
            }
        }
    }
}

// ---------------- launcher ----------------

extern "C" void kernel_launch(void* const* d_in, const int* in_sizes, int n_in,
                              void* d_out, int out_size, void* d_ws, size_t ws_size,
                              hipStream_t stream) {
    const float* x  = (const float*)d_in[0];
    const int*   ei = (const int*)d_in[1];
    const float* ew = (const float*)d_in[2];
    const float* W1 = (const float*)d_in[3];
    const float* b1 = (const float*)d_in[4];
    const float* W2 = (const float*)d_in[5];
    const float* b2 = (const float*)d_in[6];
    float* out = (float*)d_out;

    const int N = in_sizes[0] / 128;
    const int E = in_sizes[2];
    const int* src = ei;
    const int* dst = ei + E;

    const int NB = (N + NPB - 1) / NPB;        // buckets (391 for N=100k)
    const int chunk = (E + PBLK - 1) / PBLK;

    // workspace layout (16B alignment maintained)
    _Float16* gat  = (_Float16*)d_ws;                     // N*128 fp16 (gather features)
    _Float16* tt   = gat + (size_t)N * 128;               // N*128 fp16 (agg result t)
    uint2*   edgf  = (uint2*)(tt + (size_t)N * 128);      // NB*BCAP padded CSR edge records
    int*   rowbeg  = (int*)(edgf + (size_t)NB * BCAP);    // N
    int*   rowend  = rowbeg + N;               // N
    float* dinv    = (float*)(rowend + N);     // N
    int*   gcur    = (int*)(dinv + N);         // 512 (padded for alignment)
    _Float16* WT1s = (_Float16*)(gcur + 512);  // 16384 (32 KB, 16B-aligned)
    _Float16* WT2s = WT1s + 16384;             // 16384
    uint2* edg     = (uint2*)gat;              // alias (NB*BCAP uint2 = 19.2 MB < 25.6 MB)

    const int npan = (N + 31) / 32;
    const int gblocks = (npan + 3) / 4;
    const int ablocks = (N + 7) / 8;           // 4 waves/block x 2 nodes/wave
    const int sblocks = 128 + (N * 32 + 255) / 256;

    hipMemsetAsync(gcur, 0, NB * sizeof(int), stream);
    hipLaunchKernelGGL(part1, dim3(PBLK), dim3(256), 0, stream, src, dst, ew, gcur, edg, E, NB, chunk);
    hipLaunchKernelGGL(p3_bucket, dim3(NB), dim3(256), 0, stream, edg, gcur, edgf, rowbeg, rowend, dinv, N, NB);

    // WT images + gat = fp16(dinv .* x)   (overwrites edg alias — edg dead after p3)
    hipLaunchKernelGGL(wconv_split, dim3(sblocks), dim3(256), 0, stream,
                       W1, W2, WT1s, WT2s, x, dinv, gat, N * 32);

    // layer 1: tt = fp16(dinv.*agg(gat)) ; gat = fp16(dinv.*relu(tt@W1+b1))
    hipLaunchKernelGGL(agg_kernel, dim3(ablocks), dim3(256), 0, stream,
                       gat, rowbeg, rowend, edgf, dinv, (unsigned*)tt, N);
    hipLaunchKernelGGL(gemm_mfma, dim3(gblocks), dim3(256), 0, stream,
                       tt, WT1s, b1, dinv, gat, (float*)nullptr, N, 0);

    // layer 2: tt = fp16(dinv.*agg(gat)) ; out = relu(tt@W2+b2)
    hipLaunchKernelGGL(agg_kernel, dim3(ablocks), dim3(256), 0, stream,
                       gat, rowbeg, rowend, edgf, dinv, (unsigned*)tt, N);
    hipLaunchKernelGGL(gemm_mfma, dim3(gblocks), dim3(256), 0, stream,
                       tt, WT2s, b2, dinv, (_Float16*)nullptr, out, N, 1);
}